// Round 6
// baseline (144.837 us; speedup 1.0000x reference)
//
#include <hip/hip_runtime.h>

// NTXentLoss, B=8192, D=128, T=0.1, idx=0. fp32 in, fp32 scalar out.
// R12: zero-LDS, zero-barrier. R7/R9/R11 (35/38/46 us) all shared the
// per-tile vmcnt(0)+double-barrier lockstep (m233: 2-phase stall = 72% of
// critical path); intra-tile scheduling never moved it. Zib+Zjb = 4 MB =
// one XCD L2 -> LDS staging is pure overhead (Common-mistake #7, m169).
// Now: each wave independent; 32 A-rows in regs (once), sweeps 512 B-cols
// reading fragments global->VGPR straight from L2; b0/b1 register prefetch
// ping-pong + accA/accB epilogue ping-pong (static names, rule #20); NO
// __shared__, NO barriers, NO waitcnt. Same-cc blocks adjacent in blockIdx
// -> co-resident blocks share the same 128 KB B chunk (L1/L2 locality).
// ~110 VGPR, 0 LDS -> 4 waves/SIMD, all 4096 waves co-resident.
// Numerics identical to R11 (same fragments, same exp formula).

#define BB 8192
#define DD 128
#define RW 32            // rows per wave
#define CW 512           // cols per wave
#define NG (CW / 16)     // 32 column granules of 16

typedef __attribute__((ext_vector_type(8))) short short8;
typedef __attribute__((ext_vector_type(4))) float floatx4;

static __device__ __forceinline__ float wave_sum(float v) {
#pragma unroll
    for (int off = 32; off > 0; off >>= 1) v += __shfl_xor(v, off, 64);
    return v;
}

static __device__ __forceinline__ unsigned short f2bf(float f) {
    unsigned int u = __float_as_uint(f);
    return (unsigned short)((u + 0x7FFFu + ((u >> 16) & 1u)) >> 16);
}

// ---- prep: normalize rows -> bf16 + 1/norm; zero denom/out ---------------
__global__ __launch_bounds__(256) void prep_kernel(
    const float* __restrict__ zis, const float* __restrict__ zjs,
    unsigned short* __restrict__ Zib, unsigned short* __restrict__ Zjb,
    float* __restrict__ rni, float* __restrict__ rnj,
    float* __restrict__ denom, float* __restrict__ out, int nout)
{
    if (threadIdx.x < 2) denom[blockIdx.x * 2 + threadIdx.x] = 0.0f;
    if (blockIdx.x == 0 && (int)threadIdx.x < nout) out[threadIdx.x] = 0.0f;

    int wave = threadIdx.x >> 6, lane = threadIdx.x & 63;
    int row = blockIdx.x * 4 + wave;
    const float* src; unsigned short* dst; float* rn; int r;
    if (row < BB) { src = zis; dst = Zib; rn = rni; r = row; }
    else          { src = zjs; dst = Zjb; rn = rnj; r = row - BB; }
    float2 u = *(const float2*)(src + (size_t)r * DD + lane * 2);
    float s = wave_sum(u.x * u.x + u.y * u.y);
    float sc = 1.0f / sqrtf(s);
    if (lane == 0) rn[r] = sc;
    ushort2 o; o.x = f2bf(u.x * sc); o.y = f2bf(u.y * sc);
    *(ushort2*)(dst + (size_t)r * DD + lane * 2) = o;
}

// ---- barrier-free dot kernel: 4 independent waves per 256-thr block ------
// Wave owns rows [r0, r0+32) x cols [c0, c0+512). A fragments in 32 VGPR;
// B fragments read per 16-col granule: 4x global dwordx4 (16 B/lane,
// 16 rows x 64 B segments, L2/L1-resident). MFMA 16x16x32; C/D layout
// col=l15, row=quad*4+r (verified through R5..R11, absmax 0).
__global__ __launch_bounds__(256, 4) void dot_kernel(
    const unsigned short* __restrict__ Zjb,   // A: zj normalized (rows i)
    const unsigned short* __restrict__ Zib,   // B: zi normalized (cols j)
    const int* __restrict__ ilab, const int* __restrict__ jlab,
    float* __restrict__ denom)
{
    int lane = threadIdx.x & 63, wave = threadIdx.x >> 6;
    int quad = lane >> 4, l15 = lane & 15;

    // 1024 blocks: cc = blk>>6 (16 col-chunks), rg = (blk&63)*4+wave (256)
    int cc = blockIdx.x >> 6;
    int rg = ((blockIdx.x & 63) << 2) + wave;
    int r0 = rg * RW;
    int c0 = cc * CW;

    // A fragments (once, from L2): af[mt][ks], row r0+mt*16+l15, k ks*32+quad*8
    short8 af[2][4];
#pragma unroll
    for (int mt = 0; mt < 2; ++mt)
#pragma unroll
        for (int ks = 0; ks < 4; ++ks)
            af[mt][ks] = *(const short8*)(Zjb
                + (size_t)(r0 + mt * 16 + l15) * DD + ks * 32 + quad * 8);

    // j-labels for my 8 output rows
    int jrv[8];
#pragma unroll
    for (int mt = 0; mt < 2; ++mt)
#pragma unroll
        for (int r = 0; r < 4; ++r)
            jrv[mt * 4 + r] = jlab[r0 + mt * 16 + quad * 4 + r];

    float rs[2][4];
#pragma unroll
    for (int mt = 0; mt < 2; ++mt)
#pragma unroll
        for (int r = 0; r < 4; ++r) rs[mt][r] = 0.0f;

    // per-lane B base: col c0+l15, k-offset quad*8
    const unsigned short* bp = Zib + (size_t)(c0 + l15) * DD + quad * 8;
    const int* ilp = ilab + c0 + l15;

    auto LD = [&](short8 (&b)[4], int g) {
        const unsigned short* q = bp + (size_t)g * (16 * DD);
        b[0] = *(const short8*)(q);
        b[1] = *(const short8*)(q + 32);
        b[2] = *(const short8*)(q + 64);
        b[3] = *(const short8*)(q + 96);
    };
    auto GRAN = [&](short8 (&b)[4], floatx4 (&a)[2]) {
        floatx4 zz = (floatx4){0.f, 0.f, 0.f, 0.f};
        a[0] = __builtin_amdgcn_mfma_f32_16x16x32_bf16(af[0][0], b[0], zz, 0, 0, 0);
        a[1] = __builtin_amdgcn_mfma_f32_16x16x32_bf16(af[1][0], b[0], zz, 0, 0, 0);
#pragma unroll
        for (int ks = 1; ks < 4; ++ks) {
            a[0] = __builtin_amdgcn_mfma_f32_16x16x32_bf16(af[0][ks], b[ks], a[0], 0, 0, 0);
            a[1] = __builtin_amdgcn_mfma_f32_16x16x32_bf16(af[1][ks], b[ks], a[1], 0, 0, 0);
        }
    };
    auto EPI = [&](floatx4 (&a)[2], int il) {
#pragma unroll
        for (int mt = 0; mt < 2; ++mt)
#pragma unroll
            for (int r = 0; r < 4; ++r) {
                float e = __expf(fmaf(a[mt][r], 10.0f, -10.0f));
                rs[mt][r] += (il != jrv[mt * 4 + r]) ? e : 0.0f;
            }
    };

    short8 b0[4], b1[4];
    floatx4 accA[2], accB[2];
    // sentinel: exp(fmaf(-1e30,10,-10)) underflows to 0 -> first EPI adds 0
    accB[0] = (floatx4){-1e30f, -1e30f, -1e30f, -1e30f};
    accB[1] = accB[0];
    int ilA = 0, ilB = 0;

    LD(b0, 0);
    int iln0 = ilp[0], iln1 = 0;

    for (int g = 0; g < NG; g += 2) {
        if (g + 1 < NG) { LD(b1, g + 1); iln1 = ilp[(g + 1) * 16]; }
        GRAN(b0, accA); ilA = iln0;
        EPI(accB, ilB);                       // prev granule (independent regs)
        if (g + 2 < NG) { LD(b0, g + 2); iln0 = ilp[(g + 2) * 16]; }
        GRAN(b1, accB); ilB = iln1;
        EPI(accA, ilA);
    }
    EPI(accB, ilB);                           // flush granule 31

    // reduce over l15 (16 lanes) + one atomic per row per wave
#pragma unroll
    for (int mt = 0; mt < 2; ++mt)
#pragma unroll
        for (int r = 0; r < 4; ++r) {
            float v = rs[mt][r];
            v += __shfl_xor(v, 1, 64);
            v += __shfl_xor(v, 2, 64);
            v += __shfl_xor(v, 4, 64);
            v += __shfl_xor(v, 8, 64);
            if (l15 == 0)
                atomicAdd(&denom[r0 + mt * 16 + quad * 4 + r], v);
        }
}

// ---- fused pos + finalize (512 blocks, 4 rows/wave, 1 atomic/block) ------
__global__ __launch_bounds__(256) void posfinal_kernel(
    const float* __restrict__ zis, const float* __restrict__ zjs,
    const float* __restrict__ rni, const float* __restrict__ rnj,
    const float* __restrict__ denom, const float* __restrict__ wts,
    const int* __restrict__ idxp, float* __restrict__ out)
{
    int wave = threadIdx.x >> 6, lane = threadIdx.x & 63;
    int idx = idxp[0];
    float ll = 0.0f;
#pragma unroll
    for (int t = 0; t < 4; ++t) {
        int i = blockIdx.x * 16 + wave * 4 + t;
        int j = idx + i;
        float2 a  = *(const float2*)(zjs + (size_t)i * DD + lane * 2);
        float2 b2 = *(const float2*)(zis + (size_t)j * DD + lane * 2);
        float s = wave_sum(a.x * b2.x + a.y * b2.y);
        if (lane == 0) {
            float p = s * rni[j] * rnj[i] * 10.0f;
            float l = 10.0f + logf(__expf(p - 10.0f) + denom[i]) - p;
            float w = wts[j];
            ll += (l * w) / w;    // faithful to reference's weighted mean
        }
    }
    __shared__ float part[4];
    if (lane == 0) part[wave] = ll;
    __syncthreads();
    if (threadIdx.x == 0)
        atomicAdd(out, (part[0] + part[1] + part[2] + part[3]) * (1.0f / BB));
}

// ---- launch --------------------------------------------------------------
extern "C" void kernel_launch(void* const* d_in, const int* in_sizes, int n_in,
                              void* d_out, int out_size, void* d_ws, size_t ws_size,
                              hipStream_t stream) {
    const float* zis = (const float*)d_in[0];
    const float* zjs = (const float*)d_in[1];
    const int* ilab = (const int*)d_in[2];
    const int* jlab = (const int*)d_in[3];
    const float* wts = (const float*)d_in[4];
    const int* idxp = (const int*)d_in[5];
    float* out = (float*)d_out;

    float* rni   = (float*)d_ws;
    float* rnj   = rni + BB;
    float* denom = rnj + BB;
    unsigned short* Zib = (unsigned short*)(denom + BB);  // [BB][DD] bf16
    unsigned short* Zjb = Zib + (size_t)BB * DD;

    prep_kernel<<<2 * BB / 4, 256, 0, stream>>>(
        zis, zjs, Zib, Zjb, rni, rnj, denom, out, out_size);
    dot_kernel<<<(BB / RW / 4) * (BB / CW), 256, 0, stream>>>(
        Zjb, Zib, ilab, jlab, denom);
    posfinal_kernel<<<BB / 16, 256, 0, stream>>>(
        zis, zjs, rni, rnj, denom, wts, idxp, out);
}

// Round 7
// 116.807 us; speedup vs baseline: 1.2400x; 1.2400x over previous
//
#include <hip/hip_runtime.h>

// NTXentLoss, B=8192, D=128, T=0.1, idx=0. fp32 in, fp32 scalar out.
// R13: persistent B-panel. Evidence: VALU-busy ~14us and MFMA-busy ~6.5us
// constant across R11/R12; LDS versions lose to per-tile vmcnt(0)+barrier
// convoys (m233), LDS-free R12 lost to exposed L2 latency (compiler sank
// prefetch: VGPR 56) + 537MB L2 fragment traffic. Now: block stages a
// 256-col x K128 B-panel (64 KB) ONCE -> one vmcnt(0) + ONE barrier ever;
// 8 waves then fully independent (no sync of any kind): 2 chunks x 32
// A-rows from L2, 16 granules/chunk, acc ping-pong epilogue (proven).
// Waves desync -> each other's A/ds stalls covered. XOR-16 swizzle; read
// addressing identical to R11's verified path. Grid (16 row-slices x 32
// panels), row-slice fastest -> consecutive blocks stage the same panel.
// 512 blocks = exactly 2/CU; target ~115 VGPR -> 16 waves/CU.

#define BB 8192
#define DD 128
#define CP 256           // cols per block panel
#define RSL 512          // rows per block slice
#define NGR 16           // column granules per chunk (CP/16)

typedef __attribute__((ext_vector_type(8))) short short8;
typedef __attribute__((ext_vector_type(4))) float floatx4;

#define GLOBAL_AS __attribute__((address_space(1)))
#define LDS_AS    __attribute__((address_space(3)))

static __device__ __forceinline__ float wave_sum(float v) {
#pragma unroll
    for (int off = 32; off > 0; off >>= 1) v += __shfl_xor(v, off, 64);
    return v;
}

static __device__ __forceinline__ unsigned short f2bf(float f) {
    unsigned int u = __float_as_uint(f);
    return (unsigned short)((u + 0x7FFFu + ((u >> 16) & 1u)) >> 16);
}

// ---- prep: normalize rows -> bf16 + 1/norm; zero denom/out ---------------
__global__ __launch_bounds__(256) void prep_kernel(
    const float* __restrict__ zis, const float* __restrict__ zjs,
    unsigned short* __restrict__ Zib, unsigned short* __restrict__ Zjb,
    float* __restrict__ rni, float* __restrict__ rnj,
    float* __restrict__ denom, float* __restrict__ out, int nout)
{
    if (threadIdx.x < 2) denom[blockIdx.x * 2 + threadIdx.x] = 0.0f;
    if (blockIdx.x == 0 && (int)threadIdx.x < nout) out[threadIdx.x] = 0.0f;

    int wave = threadIdx.x >> 6, lane = threadIdx.x & 63;
    int row = blockIdx.x * 4 + wave;
    const float* src; unsigned short* dst; float* rn; int r;
    if (row < BB) { src = zis; dst = Zib; rn = rni; r = row; }
    else          { src = zjs; dst = Zjb; rn = rnj; r = row - BB; }
    float2 u = *(const float2*)(src + (size_t)r * DD + lane * 2);
    float s = wave_sum(u.x * u.x + u.y * u.y);
    float sc = 1.0f / sqrtf(s);
    if (lane == 0) rn[r] = sc;
    ushort2 o; o.x = f2bf(u.x * sc); o.y = f2bf(u.y * sc);
    *(ushort2*)(dst + (size_t)r * DD + lane * 2) = o;
}

// ---- persistent-panel kernel: 1 barrier total, then independent waves ----
// LDS panel: col n (row stride 256 B), phys 16-B slot p stores logical slot
// s = p ^ (n & 15) (inverse swizzle on per-lane GLOBAL source, rule #21;
// gload_lds dest linear). Fragment read: p = (ks*4+quad) ^ l15, 2 lanes per
// 16-B granule -> 2-way = free (m136). Identical addressing to R11 (absmax 0).
__global__ __launch_bounds__(512, 2) void panel_kernel(
    const unsigned short* __restrict__ Zjb,   // A: zj normalized (rows i)
    const unsigned short* __restrict__ Zib,   // B: zi normalized (cols j)
    const int* __restrict__ ilab, const int* __restrict__ jlab,
    float* __restrict__ denom)
{
    __shared__ __align__(16) unsigned short Bp[CP * DD];      // 64 KB

    int tid  = threadIdx.x;
    int lane = tid & 63, wave = tid >> 6;     // 8 waves
    int quad = lane >> 4, l15 = lane & 15;
    int c0    = blockIdx.y * CP;              // col panel (32)
    int rbase = blockIdx.x * RSL;             // row slice (16, fastest dim)

    // ---- stage panel once: 8 rounds x 512 thr x 16 B = 64 KB -------------
    {
        int nl = wave * 4 + quad;             // per-lane row within round
        int s  = l15 ^ (nl & 15);             // inverse swizzle on source
        const unsigned short* gp0 = Zib + (size_t)(c0 + nl) * DD + s * 8;
        // wave-uniform LDS base per (round, wave): region = 1 KB
#pragma unroll
        for (int u = 0; u < 8; ++u) {
            const unsigned short* gp = gp0 + (size_t)u * 32 * DD;
            unsigned short* lp = &Bp[(u * 8 + wave) * 512];
            __builtin_amdgcn_global_load_lds((const GLOBAL_AS void*)gp,
                                             (LDS_AS void*)lp, 16, 0, 0);
        }
    }
    asm volatile("s_waitcnt vmcnt(0)" ::: "memory");
    __builtin_amdgcn_s_barrier();             // the ONLY barrier

    // i-labels for the block's 256 cols (block-constant): 16 VGPR
    int ilv[NGR];
#pragma unroll
    for (int g = 0; g < NGR; ++g) ilv[g] = ilab[c0 + g * 16 + l15];

    // ---- 2 independent chunks of 32 A-rows per wave ----------------------
#pragma unroll
    for (int c = 0; c < 2; ++c) {
        int r0 = rbase + wave * 64 + c * 32;

        // A fragments from L2: af[mt][ks], row r0+mt*16+l15, k ks*32+quad*8
        short8 af[2][4];
#pragma unroll
        for (int mt = 0; mt < 2; ++mt)
#pragma unroll
            for (int ks = 0; ks < 4; ++ks)
                af[mt][ks] = *(const short8*)(Zjb
                    + (size_t)(r0 + mt * 16 + l15) * DD + ks * 32 + quad * 8);

        int jrv[8];
#pragma unroll
        for (int mt = 0; mt < 2; ++mt)
#pragma unroll
            for (int r = 0; r < 4; ++r)
                jrv[mt * 4 + r] = jlab[r0 + mt * 16 + quad * 4 + r];

        float rs[2][4];
#pragma unroll
        for (int mt = 0; mt < 2; ++mt)
#pragma unroll
            for (int r = 0; r < 4; ++r) rs[mt][r] = 0.0f;

        auto GRAN = [&](int g, floatx4 (&a)[2]) {
            const unsigned short* rb = &Bp[(g * 16 + l15) * DD];
            short8 b[4];
#pragma unroll
            for (int ks = 0; ks < 4; ++ks)
                b[ks] = *(const short8*)(rb + (((ks * 4 + quad) ^ l15) * 8));
            floatx4 zz = (floatx4){0.f, 0.f, 0.f, 0.f};
            a[0] = __builtin_amdgcn_mfma_f32_16x16x32_bf16(af[0][0], b[0], zz, 0, 0, 0);
            a[1] = __builtin_amdgcn_mfma_f32_16x16x32_bf16(af[1][0], b[0], zz, 0, 0, 0);
#pragma unroll
            for (int ks = 1; ks < 4; ++ks) {
                a[0] = __builtin_amdgcn_mfma_f32_16x16x32_bf16(af[0][ks], b[ks], a[0], 0, 0, 0);
                a[1] = __builtin_amdgcn_mfma_f32_16x16x32_bf16(af[1][ks], b[ks], a[1], 0, 0, 0);
            }
        };
        auto EPI = [&](floatx4 (&a)[2], int il) {
#pragma unroll
            for (int mt = 0; mt < 2; ++mt)
#pragma unroll
                for (int r = 0; r < 4; ++r) {
                    float e = __expf(fmaf(a[mt][r], 10.0f, -10.0f));
                    rs[mt][r] += (il != jrv[mt * 4 + r]) ? e : 0.0f;
                }
        };

        floatx4 accA[2], accB[2];
        // sentinel: exp(fmaf(-1e30,10,-10)) underflows to 0 -> first EPI += 0
        accB[0] = (floatx4){-1e30f, -1e30f, -1e30f, -1e30f};
        accB[1] = accB[0];
        int ilB = 0;

        __builtin_amdgcn_s_setprio(1);
#pragma unroll
        for (int g = 0; g < NGR; g += 2) {
            GRAN(g,     accA); EPI(accB, ilB);       // epi of prev granule
            GRAN(g + 1, accB); EPI(accA, ilv[g]);
            ilB = ilv[g + 1];
        }
        __builtin_amdgcn_s_setprio(0);
        EPI(accB, ilB);                              // flush granule 15

        // reduce over l15 (16 lanes) + atomics for this chunk's 32 rows
#pragma unroll
        for (int mt = 0; mt < 2; ++mt)
#pragma unroll
            for (int r = 0; r < 4; ++r) {
                float v = rs[mt][r];
                v += __shfl_xor(v, 1, 64);
                v += __shfl_xor(v, 2, 64);
                v += __shfl_xor(v, 4, 64);
                v += __shfl_xor(v, 8, 64);
                if (l15 == 0)
                    atomicAdd(&denom[r0 + mt * 16 + quad * 4 + r], v);
            }
    }
}

// ---- fused pos + finalize (512 blocks, 4 rows/wave, 1 atomic/block) ------
__global__ __launch_bounds__(256) void posfinal_kernel(
    const float* __restrict__ zis, const float* __restrict__ zjs,
    const float* __restrict__ rni, const float* __restrict__ rnj,
    const float* __restrict__ denom, const float* __restrict__ wts,
    const int* __restrict__ idxp, float* __restrict__ out)
{
    int wave = threadIdx.x >> 6, lane = threadIdx.x & 63;
    int idx = idxp[0];
    float ll = 0.0f;
#pragma unroll
    for (int t = 0; t < 4; ++t) {
        int i = blockIdx.x * 16 + wave * 4 + t;
        int j = idx + i;
        float2 a  = *(const float2*)(zjs + (size_t)i * DD + lane * 2);
        float2 b2 = *(const float2*)(zis + (size_t)j * DD + lane * 2);
        float s = wave_sum(a.x * b2.x + a.y * b2.y);
        if (lane == 0) {
            float p = s * rni[j] * rnj[i] * 10.0f;
            float l = 10.0f + logf(__expf(p - 10.0f) + denom[i]) - p;
            float w = wts[j];
            ll += (l * w) / w;    // faithful to reference's weighted mean
        }
    }
    __shared__ float part[4];
    if (lane == 0) part[wave] = ll;
    __syncthreads();
    if (threadIdx.x == 0)
        atomicAdd(out, (part[0] + part[1] + part[2] + part[3]) * (1.0f / BB));
}

// ---- launch --------------------------------------------------------------
extern "C" void kernel_launch(void* const* d_in, const int* in_sizes, int n_in,
                              void* d_out, int out_size, void* d_ws, size_t ws_size,
                              hipStream_t stream) {
    const float* zis = (const float*)d_in[0];
    const float* zjs = (const float*)d_in[1];
    const int* ilab = (const int*)d_in[2];
    const int* jlab = (const int*)d_in[3];
    const float* wts = (const float*)d_in[4];
    const int* idxp = (const int*)d_in[5];
    float* out = (float*)d_out;

    float* rni   = (float*)d_ws;
    float* rnj   = rni + BB;
    float* denom = rnj + BB;
    unsigned short* Zib = (unsigned short*)(denom + BB);  // [BB][DD] bf16
    unsigned short* Zjb = Zib + (size_t)BB * DD;

    prep_kernel<<<2 * BB / 4, 256, 0, stream>>>(
        zis, zjs, Zib, Zjb, rni, rnj, denom, out, out_size);
    panel_kernel<<<dim3(BB / RSL, BB / CP), 512, 0, stream>>>(
        Zjb, Zib, ilab, jlab, denom);
    posfinal_kernel<<<BB / 16, 256, 0, stream>>>(
        zis, zjs, rni, rnj, denom, wts, idxp, out);
}

// Round 8
// 110.749 us; speedup vs baseline: 1.3078x; 1.0547x over previous
//
#include <hip/hip_runtime.h>

// NTXentLoss, B=8192, D=128, T=0.1, idx=0. fp32 in, fp32 scalar out.
// R14: R13 minus the spill. R13 hit the (512,2) VGPR cap exactly (128) and
// spilled ~14 MB/dispatch (WRITE 16.6 vs 2 MB logical) from ~140 live regs.
// Structure retained (validated): stage 256-col x K128 B-panel once, ONE
// vmcnt(0)+barrier ever, 8 waves then fully independent (TLP, not lockstep).
// Register diet: (a) single acc - R11 proved the WAR-break ping-pong is
// worthless (-16); (b) i-labels -> 1 KB LDS, per-granule broadcast read
// with 1-granule lookahead (-16); (c) exp folded to exp2 (mul-by-log2e
// fused into the existing fmaf). ~105 live VGPR < 128 cap -> no spill.

#define BB 8192
#define DD 128
#define CP 256           // cols per block panel
#define RSL 512          // rows per block slice
#define NGR 16           // column granules per chunk (CP/16)

typedef __attribute__((ext_vector_type(8))) short short8;
typedef __attribute__((ext_vector_type(4))) float floatx4;

#define GLOBAL_AS __attribute__((address_space(1)))
#define LDS_AS    __attribute__((address_space(3)))

#define L2E10 14.4269504088896340f   // 10 * log2(e)

static __device__ __forceinline__ float wave_sum(float v) {
#pragma unroll
    for (int off = 32; off > 0; off >>= 1) v += __shfl_xor(v, off, 64);
    return v;
}

static __device__ __forceinline__ unsigned short f2bf(float f) {
    unsigned int u = __float_as_uint(f);
    return (unsigned short)((u + 0x7FFFu + ((u >> 16) & 1u)) >> 16);
}

// ---- prep: normalize rows -> bf16 + 1/norm; zero denom/out ---------------
__global__ __launch_bounds__(256) void prep_kernel(
    const float* __restrict__ zis, const float* __restrict__ zjs,
    unsigned short* __restrict__ Zib, unsigned short* __restrict__ Zjb,
    float* __restrict__ rni, float* __restrict__ rnj,
    float* __restrict__ denom, float* __restrict__ out, int nout)
{
    if (threadIdx.x < 2) denom[blockIdx.x * 2 + threadIdx.x] = 0.0f;
    if (blockIdx.x == 0 && (int)threadIdx.x < nout) out[threadIdx.x] = 0.0f;

    int wave = threadIdx.x >> 6, lane = threadIdx.x & 63;
    int row = blockIdx.x * 4 + wave;
    const float* src; unsigned short* dst; float* rn; int r;
    if (row < BB) { src = zis; dst = Zib; rn = rni; r = row; }
    else          { src = zjs; dst = Zjb; rn = rnj; r = row - BB; }
    float2 u = *(const float2*)(src + (size_t)r * DD + lane * 2);
    float s = wave_sum(u.x * u.x + u.y * u.y);
    float sc = 1.0f / sqrtf(s);
    if (lane == 0) rn[r] = sc;
    ushort2 o; o.x = f2bf(u.x * sc); o.y = f2bf(u.y * sc);
    *(ushort2*)(dst + (size_t)r * DD + lane * 2) = o;
}

// ---- persistent-panel kernel: 1 barrier total, then independent waves ----
// LDS panel: col n (row stride 256 B), phys 16-B slot p stores logical slot
// s = p ^ (n & 15) (inverse swizzle on per-lane GLOBAL source, rule #21;
// gload_lds dest linear). Fragment read: p = (ks*4+quad) ^ l15 -> measured
// 0 bank conflicts (R13). Addressing identical to R13 (absmax 0).
__global__ __launch_bounds__(512, 2) void panel_kernel(
    const unsigned short* __restrict__ Zjb,   // A: zj normalized (rows i)
    const unsigned short* __restrict__ Zib,   // B: zi normalized (cols j)
    const int* __restrict__ ilab, const int* __restrict__ jlab,
    float* __restrict__ denom)
{
    __shared__ __align__(16) unsigned short Bp[CP * DD];      // 64 KB
    __shared__ int Il[CP];                                    // 1 KB

    int tid  = threadIdx.x;
    int lane = tid & 63, wave = tid >> 6;     // 8 waves
    int quad = lane >> 4, l15 = lane & 15;
    int c0    = blockIdx.y * CP;              // col panel (32)
    int rbase = blockIdx.x * RSL;             // row slice (16, fastest dim)

    // ---- stage panel + labels once ---------------------------------------
    {
        int nl = wave * 4 + quad;             // per-lane row within round
        int s  = l15 ^ (nl & 15);             // inverse swizzle on source
        const unsigned short* gp0 = Zib + (size_t)(c0 + nl) * DD + s * 8;
#pragma unroll
        for (int u = 0; u < 8; ++u) {
            const unsigned short* gp = gp0 + (size_t)u * 32 * DD;
            unsigned short* lp = &Bp[(u * 8 + wave) * 512];
            __builtin_amdgcn_global_load_lds((const GLOBAL_AS void*)gp,
                                             (LDS_AS void*)lp, 16, 0, 0);
        }
    }
    if (tid < CP) Il[tid] = ilab[c0 + tid];
    asm volatile("s_waitcnt vmcnt(0) lgkmcnt(0)" ::: "memory");
    __builtin_amdgcn_s_barrier();             // the ONLY barrier

    // ---- 2 independent chunks of 32 A-rows per wave ----------------------
#pragma unroll
    for (int c = 0; c < 2; ++c) {
        int r0 = rbase + wave * 64 + c * 32;

        // A fragments from L2: af[mt][ks], row r0+mt*16+l15, k ks*32+quad*8
        short8 af[2][4];
#pragma unroll
        for (int mt = 0; mt < 2; ++mt)
#pragma unroll
            for (int ks = 0; ks < 4; ++ks)
                af[mt][ks] = *(const short8*)(Zjb
                    + (size_t)(r0 + mt * 16 + l15) * DD + ks * 32 + quad * 8);

        int jrv[8];
#pragma unroll
        for (int mt = 0; mt < 2; ++mt)
#pragma unroll
            for (int r = 0; r < 4; ++r)
                jrv[mt * 4 + r] = jlab[r0 + mt * 16 + quad * 4 + r];

        float rs[2][4];
#pragma unroll
        for (int mt = 0; mt < 2; ++mt)
#pragma unroll
            for (int r = 0; r < 4; ++r) rs[mt][r] = 0.0f;

        floatx4 acc[2];
        int iln = Il[l15];                    // granule-0 labels (lookahead)

        __builtin_amdgcn_s_setprio(1);
#pragma unroll
        for (int g = 0; g < NGR; ++g) {
            // GRAN: 4 swizzled ds_read_b128 + 8 MFMA -> acc
            const unsigned short* rb = &Bp[(g * 16 + l15) * DD];
            short8 b[4];
#pragma unroll
            for (int ks = 0; ks < 4; ++ks)
                b[ks] = *(const short8*)(rb + (((ks * 4 + quad) ^ l15) * 8));
            floatx4 zz = (floatx4){0.f, 0.f, 0.f, 0.f};
            acc[0] = __builtin_amdgcn_mfma_f32_16x16x32_bf16(af[0][0], b[0], zz, 0, 0, 0);
            acc[1] = __builtin_amdgcn_mfma_f32_16x16x32_bf16(af[1][0], b[0], zz, 0, 0, 0);
#pragma unroll
            for (int ks = 1; ks < 4; ++ks) {
                acc[0] = __builtin_amdgcn_mfma_f32_16x16x32_bf16(af[0][ks], b[ks], acc[0], 0, 0, 0);
                acc[1] = __builtin_amdgcn_mfma_f32_16x16x32_bf16(af[1][ks], b[ks], acc[1], 0, 0, 0);
            }
            int ilc = iln;
            if (g + 1 < NGR) iln = Il[(g + 1) * 16 + l15];   // lookahead
            // EPI: e = 2^(c*10*log2e - 10*log2e) = exp(10c-10); mask; add
#pragma unroll
            for (int mt = 0; mt < 2; ++mt)
#pragma unroll
                for (int r = 0; r < 4; ++r) {
                    float e = __builtin_amdgcn_exp2f(
                        fmaf(acc[mt][r], L2E10, -L2E10));
                    rs[mt][r] += (ilc != jrv[mt * 4 + r]) ? e : 0.0f;
                }
        }
        __builtin_amdgcn_s_setprio(0);

        // reduce over l15 (16 lanes) + atomics for this chunk's 32 rows
#pragma unroll
        for (int mt = 0; mt < 2; ++mt)
#pragma unroll
            for (int r = 0; r < 4; ++r) {
                float v = rs[mt][r];
                v += __shfl_xor(v, 1, 64);
                v += __shfl_xor(v, 2, 64);
                v += __shfl_xor(v, 4, 64);
                v += __shfl_xor(v, 8, 64);
                if (l15 == 0)
                    atomicAdd(&denom[r0 + mt * 16 + quad * 4 + r], v);
            }
    }
}

// ---- fused pos + finalize (512 blocks, 4 rows/wave, 1 atomic/block) ------
__global__ __launch_bounds__(256) void posfinal_kernel(
    const float* __restrict__ zis, const float* __restrict__ zjs,
    const float* __restrict__ rni, const float* __restrict__ rnj,
    const float* __restrict__ denom, const float* __restrict__ wts,
    const int* __restrict__ idxp, float* __restrict__ out)
{
    int wave = threadIdx.x >> 6, lane = threadIdx.x & 63;
    int idx = idxp[0];
    float ll = 0.0f;
#pragma unroll
    for (int t = 0; t < 4; ++t) {
        int i = blockIdx.x * 16 + wave * 4 + t;
        int j = idx + i;
        float2 a  = *(const float2*)(zjs + (size_t)i * DD + lane * 2);
        float2 b2 = *(const float2*)(zis + (size_t)j * DD + lane * 2);
        float s = wave_sum(a.x * b2.x + a.y * b2.y);
        if (lane == 0) {
            float p = s * rni[j] * rnj[i] * 10.0f;
            float l = 10.0f + logf(__expf(p - 10.0f) + denom[i]) - p;
            float w = wts[j];
            ll += (l * w) / w;    // faithful to reference's weighted mean
        }
    }
    __shared__ float part[4];
    if (lane == 0) part[wave] = ll;
    __syncthreads();
    if (threadIdx.x == 0)
        atomicAdd(out, (part[0] + part[1] + part[2] + part[3]) * (1.0f / BB));
}

// ---- launch --------------------------------------------------------------
extern "C" void kernel_launch(void* const* d_in, const int* in_sizes, int n_in,
                              void* d_out, int out_size, void* d_ws, size_t ws_size,
                              hipStream_t stream) {
    const float* zis = (const float*)d_in[0];
    const float* zjs = (const float*)d_in[1];
    const int* ilab = (const int*)d_in[2];
    const int* jlab = (const int*)d_in[3];
    const float* wts = (const float*)d_in[4];
    const int* idxp = (const int*)d_in[5];
    float* out = (float*)d_out;

    float* rni   = (float*)d_ws;
    float* rnj   = rni + BB;
    float* denom = rnj + BB;
    unsigned short* Zib = (unsigned short*)(denom + BB);  // [BB][DD] bf16
    unsigned short* Zjb = Zib + (size_t)BB * DD;

    prep_kernel<<<2 * BB / 4, 256, 0, stream>>>(
        zis, zjs, Zib, Zjb, rni, rnj, denom, out, out_size);
    panel_kernel<<<dim3(BB / RSL, BB / CP), 512, 0, stream>>>(
        Zjb, Zib, ilab, jlab, denom);
    posfinal_kernel<<<BB / 16, 256, 0, stream>>>(
        zis, zjs, rni, rnj, denom, wts, idxp, out);
}

// Round 9
// 109.837 us; speedup vs baseline: 1.3187x; 1.0083x over previous
//
#include <hip/hip_runtime.h>

// NTXentLoss, B=8192, D=128, T=0.1, idx=0. fp32 in, fp32 scalar out.
// R15: kill inner-loop VALU bookkeeping. Audit: measured VALU-busy ~14us vs
// ~5us of actual epilogue math -> ~2/3 is per-granule addressing (lane-dep
// swizzle recomputed each granule) + exposed ds lgkm stalls (reads issued
// right before first use). Fix: (1) 4 granule-invariant swizzled base ptrs
// rb0..rb3 hoisted; granule reads at compile-time offset g*4096 -> folded
// into ds_read imm offsets, zero addr VALU in loop; (2) b0/b1 prefetch-by-
// one-granule (static names, rule #20; single acc - R11 proved ping-pong
// useless) -> ds latency hides under MFMA+EPI, compiler emits counted
// lgkmcnt; (3) Il reads via base+imm too. ~105 VGPR < 128 cap.
// Stage/swizzle/barrier byte-identical to R14 (absmax 0 verified).

#define BB 8192
#define DD 128
#define CP 256           // cols per block panel
#define RSL 512          // rows per block slice
#define NGR 16           // column granules per chunk (CP/16)

typedef __attribute__((ext_vector_type(8))) short short8;
typedef __attribute__((ext_vector_type(4))) float floatx4;

#define GLOBAL_AS __attribute__((address_space(1)))
#define LDS_AS    __attribute__((address_space(3)))

#define L2E10 14.4269504088896340f   // 10 * log2(e)

static __device__ __forceinline__ float wave_sum(float v) {
#pragma unroll
    for (int off = 32; off > 0; off >>= 1) v += __shfl_xor(v, off, 64);
    return v;
}

static __device__ __forceinline__ unsigned short f2bf(float f) {
    unsigned int u = __float_as_uint(f);
    return (unsigned short)((u + 0x7FFFu + ((u >> 16) & 1u)) >> 16);
}

// ---- prep: normalize rows -> bf16 + 1/norm; zero denom/out ---------------
__global__ __launch_bounds__(256) void prep_kernel(
    const float* __restrict__ zis, const float* __restrict__ zjs,
    unsigned short* __restrict__ Zib, unsigned short* __restrict__ Zjb,
    float* __restrict__ rni, float* __restrict__ rnj,
    float* __restrict__ denom, float* __restrict__ out, int nout)
{
    if (threadIdx.x < 2) denom[blockIdx.x * 2 + threadIdx.x] = 0.0f;
    if (blockIdx.x == 0 && (int)threadIdx.x < nout) out[threadIdx.x] = 0.0f;

    int wave = threadIdx.x >> 6, lane = threadIdx.x & 63;
    int row = blockIdx.x * 4 + wave;
    const float* src; unsigned short* dst; float* rn; int r;
    if (row < BB) { src = zis; dst = Zib; rn = rni; r = row; }
    else          { src = zjs; dst = Zjb; rn = rnj; r = row - BB; }
    float2 u = *(const float2*)(src + (size_t)r * DD + lane * 2);
    float s = wave_sum(u.x * u.x + u.y * u.y);
    float sc = 1.0f / sqrtf(s);
    if (lane == 0) rn[r] = sc;
    ushort2 o; o.x = f2bf(u.x * sc); o.y = f2bf(u.y * sc);
    *(ushort2*)(dst + (size_t)r * DD + lane * 2) = o;
}

// ---- persistent-panel kernel: 1 barrier total, then independent waves ----
// LDS panel: col n (row stride 256 B), phys 16-B slot p stores logical slot
// s = p ^ (n & 15) (inverse swizzle on per-lane GLOBAL source, rule #21;
// gload_lds dest linear). Fragment read: p = (ks*4+quad) ^ l15 -> 0 bank
// conflicts measured (R13). Addressing identical to R13/R14 (absmax 0).
__global__ __launch_bounds__(512, 2) void panel_kernel(
    const unsigned short* __restrict__ Zjb,   // A: zj normalized (rows i)
    const unsigned short* __restrict__ Zib,   // B: zi normalized (cols j)
    const int* __restrict__ ilab, const int* __restrict__ jlab,
    float* __restrict__ denom)
{
    __shared__ __align__(16) unsigned short Bp[CP * DD];      // 64 KB
    __shared__ int Il[CP];                                    // 1 KB

    int tid  = threadIdx.x;
    int lane = tid & 63, wave = tid >> 6;     // 8 waves
    int quad = lane >> 4, l15 = lane & 15;
    int c0    = blockIdx.y * CP;              // col panel (32)
    int rbase = blockIdx.x * RSL;             // row slice (16, fastest dim)

    // ---- stage panel + labels once ---------------------------------------
    {
        int nl = wave * 4 + quad;             // per-lane row within round
        int s  = l15 ^ (nl & 15);             // inverse swizzle on source
        const unsigned short* gp0 = Zib + (size_t)(c0 + nl) * DD + s * 8;
#pragma unroll
        for (int u = 0; u < 8; ++u) {
            const unsigned short* gp = gp0 + (size_t)u * 32 * DD;
            unsigned short* lp = &Bp[(u * 8 + wave) * 512];
            __builtin_amdgcn_global_load_lds((const GLOBAL_AS void*)gp,
                                             (LDS_AS void*)lp, 16, 0, 0);
        }
    }
    if (tid < CP) Il[tid] = ilab[c0 + tid];
    asm volatile("s_waitcnt vmcnt(0) lgkmcnt(0)" ::: "memory");
    __builtin_amdgcn_s_barrier();             // the ONLY barrier

    // granule-invariant swizzled LDS bases (4 VGPR): granule g adds g*4096 B
    // -> compile-time imm offset on ds_read_b128 (max 15*4096+240 < 64K).
    const unsigned short* rb0 = &Bp[l15 * DD + (((0 * 4 + quad) ^ l15) * 8)];
    const unsigned short* rb1 = &Bp[l15 * DD + (((1 * 4 + quad) ^ l15) * 8)];
    const unsigned short* rb2 = &Bp[l15 * DD + (((2 * 4 + quad) ^ l15) * 8)];
    const unsigned short* rb3 = &Bp[l15 * DD + (((3 * 4 + quad) ^ l15) * 8)];
    const int* ilb = &Il[l15];                // + g*16 -> imm offset g*64

#define LDB(bx, g) do {                                       \
        bx[0] = *(const short8*)(rb0 + (g) * 16 * DD);        \
        bx[1] = *(const short8*)(rb1 + (g) * 16 * DD);        \
        bx[2] = *(const short8*)(rb2 + (g) * 16 * DD);        \
        bx[3] = *(const short8*)(rb3 + (g) * 16 * DD);        \
    } while (0)

#define MFMA8(bx) do {                                                          \
        floatx4 zz = (floatx4){0.f, 0.f, 0.f, 0.f};                             \
        acc[0] = __builtin_amdgcn_mfma_f32_16x16x32_bf16(af[0][0], bx[0], zz, 0, 0, 0); \
        acc[1] = __builtin_amdgcn_mfma_f32_16x16x32_bf16(af[1][0], bx[0], zz, 0, 0, 0); \
        acc[0] = __builtin_amdgcn_mfma_f32_16x16x32_bf16(af[0][1], bx[1], acc[0], 0, 0, 0); \
        acc[1] = __builtin_amdgcn_mfma_f32_16x16x32_bf16(af[1][1], bx[1], acc[1], 0, 0, 0); \
        acc[0] = __builtin_amdgcn_mfma_f32_16x16x32_bf16(af[0][2], bx[2], acc[0], 0, 0, 0); \
        acc[1] = __builtin_amdgcn_mfma_f32_16x16x32_bf16(af[1][2], bx[2], acc[1], 0, 0, 0); \
        acc[0] = __builtin_amdgcn_mfma_f32_16x16x32_bf16(af[0][3], bx[3], acc[0], 0, 0, 0); \
        acc[1] = __builtin_amdgcn_mfma_f32_16x16x32_bf16(af[1][3], bx[3], acc[1], 0, 0, 0); \
    } while (0)

#define EPI(ilc) do {                                         \
        _Pragma("unroll")                                     \
        for (int mt = 0; mt < 2; ++mt)                        \
            _Pragma("unroll")                                 \
            for (int r = 0; r < 4; ++r) {                     \
                float e = __builtin_amdgcn_exp2f(             \
                    fmaf(acc[mt][r], L2E10, -L2E10));         \
                rs[mt][r] += ((ilc) != jrv[mt * 4 + r]) ? e : 0.0f; \
            }                                                 \
    } while (0)

    // ---- 2 independent chunks of 32 A-rows per wave ----------------------
#pragma unroll
    for (int c = 0; c < 2; ++c) {
        int r0 = rbase + wave * 64 + c * 32;

        // A fragments from L2: af[mt][ks], row r0+mt*16+l15, k ks*32+quad*8
        short8 af[2][4];
#pragma unroll
        for (int mt = 0; mt < 2; ++mt)
#pragma unroll
            for (int ks = 0; ks < 4; ++ks)
                af[mt][ks] = *(const short8*)(Zjb
                    + (size_t)(r0 + mt * 16 + l15) * DD + ks * 32 + quad * 8);

        int jrv[8];
#pragma unroll
        for (int mt = 0; mt < 2; ++mt)
#pragma unroll
            for (int r = 0; r < 4; ++r)
                jrv[mt * 4 + r] = jlab[r0 + mt * 16 + quad * 4 + r];

        float rs[2][4];
#pragma unroll
        for (int mt = 0; mt < 2; ++mt)
#pragma unroll
            for (int r = 0; r < 4; ++r) rs[mt][r] = 0.0f;

        floatx4 acc[2];
        short8 b0[4], b1[4];
        LDB(b0, 0);
        int iln = ilb[0];

        __builtin_amdgcn_s_setprio(1);
#pragma unroll
        for (int g = 0; g < NGR; g += 2) {
            LDB(b1, g + 1);                       // prefetch odd granule
            int il0 = iln; iln = ilb[(g + 1) * 16];
            MFMA8(b0);
            EPI(il0);
            if (g + 2 < NGR) LDB(b0, g + 2);      // prefetch next even
            int il1 = iln;
            if (g + 2 < NGR) iln = ilb[(g + 2) * 16];
            MFMA8(b1);
            EPI(il1);
        }
        __builtin_amdgcn_s_setprio(0);

        // reduce over l15 (16 lanes) + atomics for this chunk's 32 rows
#pragma unroll
        for (int mt = 0; mt < 2; ++mt)
#pragma unroll
            for (int r = 0; r < 4; ++r) {
                float v = rs[mt][r];
                v += __shfl_xor(v, 1, 64);
                v += __shfl_xor(v, 2, 64);
                v += __shfl_xor(v, 4, 64);
                v += __shfl_xor(v, 8, 64);
                if (l15 == 0)
                    atomicAdd(&denom[r0 + mt * 16 + quad * 4 + r], v);
            }
    }
#undef LDB
#undef MFMA8
#undef EPI
}

// ---- fused pos + finalize (512 blocks, 4 rows/wave, 1 atomic/block) ------
__global__ __launch_bounds__(256) void posfinal_kernel(
    const float* __restrict__ zis, const float* __restrict__ zjs,
    const float* __restrict__ rni, const float* __restrict__ rnj,
    const float* __restrict__ denom, const float* __restrict__ wts,
    const int* __restrict__ idxp, float* __restrict__ out)
{
    int wave = threadIdx.x >> 6, lane = threadIdx.x & 63;
    int idx = idxp[0];
    float ll = 0.0f;
#pragma unroll
    for (int t = 0; t < 4; ++t) {
        int i = blockIdx.x * 16 + wave * 4 + t;
        int j = idx + i;
        float2 a  = *(const float2*)(zjs + (size_t)i * DD + lane * 2);
        float2 b2 = *(const float2*)(zis + (size_t)j * DD + lane * 2);
        float s = wave_sum(a.x * b2.x + a.y * b2.y);
        if (lane == 0) {
            float p = s * rni[j] * rnj[i] * 10.0f;
            float l = 10.0f + logf(__expf(p - 10.0f) + denom[i]) - p;
            float w = wts[j];
            ll += (l * w) / w;    // faithful to reference's weighted mean
        }
    }
    __shared__ float part[4];
    if (lane == 0) part[wave] = ll;
    __syncthreads();
    if (threadIdx.x == 0)
        atomicAdd(out, (part[0] + part[1] + part[2] + part[3]) * (1.0f / BB));
}

// ---- launch --------------------------------------------------------------
extern "C" void kernel_launch(void* const* d_in, const int* in_sizes, int n_in,
                              void* d_out, int out_size, void* d_ws, size_t ws_size,
                              hipStream_t stream) {
    const float* zis = (const float*)d_in[0];
    const float* zjs = (const float*)d_in[1];
    const int* ilab = (const int*)d_in[2];
    const int* jlab = (const int*)d_in[3];
    const float* wts = (const float*)d_in[4];
    const int* idxp = (const int*)d_in[5];
    float* out = (float*)d_out;

    float* rni   = (float*)d_ws;
    float* rnj   = rni + BB;
    float* denom = rnj + BB;
    unsigned short* Zib = (unsigned short*)(denom + BB);  // [BB][DD] bf16
    unsigned short* Zjb = Zib + (size_t)BB * DD;

    prep_kernel<<<2 * BB / 4, 256, 0, stream>>>(
        zis, zjs, Zib, Zjb, rni, rnj, denom, out, out_size);
    panel_kernel<<<dim3(BB / RSL, BB / CP), 512, 0, stream>>>(
        Zjb, Zib, ilab, jlab, denom);
    posfinal_kernel<<<BB / 16, 256, 0, stream>>>(
        zis, zjs, rni, rnj, denom, wts, idxp, out);
}